// Round 7
// baseline (663.192 us; speedup 1.0000x reference)
//
#include <hip/hip_runtime.h>
#include <hip/hip_bf16.h>
#include <stdint.h>

#define NROWS 131072
#define EPSBN 1e-5f
#define LEAKK 0.33f

typedef __bf16 bf16x8_t __attribute__((ext_vector_type(8)));
typedef float  f32x4_t  __attribute__((ext_vector_type(4)));

__device__ __forceinline__ float leaky_f(float x) { return fmaxf(x, LEAKK * x); }

#define GLDS16(g, l)                                                          \
    __builtin_amdgcn_global_load_lds(                                         \
        (const __attribute__((address_space(1))) void*)(g),                   \
        (__attribute__((address_space(3))) void*)(l), 16, 0, 0)

// gfx9 waitcnt imm: vmcnt[3:0]|[15:14], expcnt[6:4], lgkmcnt[11:8]
#define WAIT_VM16  0x4F70   // vmcnt<=16, lgkm/exp off
#define WAIT_VM12  0x0F7C
#define WAIT_VM8   0x0F78
#define WAIT_VM4   0x0F74
#define WAIT_VM0   0x0F70
#define WAIT_LGKM0 0xC07F   // lgkmcnt==0, vmcnt/exp off
#define CFENCE() asm volatile("" ::: "memory")

// Gather-GEMM conv, 5-deep async glds ring.
// out[n,d] = sum_k sum_c src[cidxT[k][n],c] * w[k,c,d]; cidxT premasked
// (masked-out -> row NROWS = zeros). Block: 64 rows, 4 waves, wave tile 16x64.
// All idx loaded to VGPRs up front (no VGPR global loads once the glds queue
// is live -- vmcnt retires in order). Ring slot k%5 holds stage k (8KB A rows
// + 8KB B slab); iter k waits vmcnt(16) (never a full drain until the tail),
// computes, restages k+5 into the freed slot AFTER an lgkmcnt(0)+barrier
// (closes the ds_read-vs-DMA-overwrite race). XOR chunk swizzle keeps
// ds_read_b128 at 2-way conflicts. LDS = 80KB -> 2 blocks/CU.
__global__ __launch_bounds__(256, 2) void conv_kernel(
    const __bf16* __restrict__ src,      // (NROWS+1) x 64, row NROWS = zeros
    const int* __restrict__ cidxT,       // [9][NROWS]
    const __bf16* __restrict__ wt,       // [9][64 d][64 c]
    __bf16* __restrict__ dst,
    float* __restrict__ stat_out)
{
    __shared__ char SL[5][16384];        // [stage%5][A 8KB | B 8KB]

    const int tid  = threadIdx.x;
    const int lane = tid & 63;
    const int wv   = tid >> 6;
    const int quad = lane >> 4;
    const int l15  = lane & 15;
    const int row0 = blockIdx.x << 6;            // 64 rows/block
    const int srow = tid >> 3;                   // staging row-part (0..31)
    const int cg   = (tid & 7) ^ (srow & 7);     // swizzled global chunk
    const int ldsw = (tid & 192) << 4;           // wv*1024 wave-uniform base
    const int sxor = l15 & 7;

    const char* srcb = (const char*)src;
    const char* wtb  = (const char*)wt;

    // all idx up front; nothing else enters the vmcnt queue after the glds start
    int ix[9][2];
#pragma unroll
    for (int k = 0; k < 9; ++k)
#pragma unroll
        for (int i = 0; i < 2; ++i)
            ix[k][i] = cidxT[k * NROWS + row0 + (i << 5) + srow];
    CFENCE();

    f32x4_t acc[4];
#pragma unroll
    for (int nt = 0; nt < 4; ++nt) acc[nt] = (f32x4_t){0.f, 0.f, 0.f, 0.f};

    // prologue: stages 0..4 (4 glds each: 2 A-gather + 2 B)
#pragma unroll
    for (int s = 0; s < 5; ++s) {
#pragma unroll
        for (int i = 0; i < 2; ++i)
            GLDS16(srcb + ((size_t)ix[s][i] << 7) + (cg << 4),
                   &SL[s][(i << 12) + ldsw]);
#pragma unroll
        for (int i = 0; i < 2; ++i)
            GLDS16(wtb + ((size_t)s << 13) + (i << 12) + ((tid >> 3) << 7) + (cg << 4),
                   &SL[s][8192 + (i << 12) + ldsw]);
        CFENCE();
    }

#pragma unroll
    for (int k = 0; k < 9; ++k) {
        // wait own stage-k glds (stages k+1.. stay in flight), then sync waves
        if (k < 5)       __builtin_amdgcn_s_waitcnt(WAIT_VM16);
        else if (k == 5) __builtin_amdgcn_s_waitcnt(WAIT_VM12);
        else if (k == 6) __builtin_amdgcn_s_waitcnt(WAIT_VM8);
        else if (k == 7) __builtin_amdgcn_s_waitcnt(WAIT_VM4);
        else             __builtin_amdgcn_s_waitcnt(WAIT_VM0);
        __builtin_amdgcn_s_barrier();
        CFENCE();

        const char* As = SL[k % 5];
        const char* Bs = As + 8192;
        bf16x8_t af[2], bq[4][2];
#pragma unroll
        for (int ks = 0; ks < 2; ++ks) {
            const int slot = ((quad | (ks << 2)) ^ sxor) << 4;
            af[ks] = *(const bf16x8_t*)(As + (((wv << 4) + l15) << 7) + slot);
#pragma unroll
            for (int nt = 0; nt < 4; ++nt)
                bq[nt][ks] = *(const bf16x8_t*)(Bs + (((nt << 4) + l15) << 7) + slot);
        }
#pragma unroll
        for (int ks = 0; ks < 2; ++ks)
#pragma unroll
            for (int nt = 0; nt < 4; ++nt)
                acc[nt] = __builtin_amdgcn_mfma_f32_16x16x32_bf16(
                    af[ks], bq[nt][ks], acc[nt], 0, 0, 0);

        // restage k+5 into the slot just consumed. MUST drain own ds_reads
        // (lgkmcnt 0) before the barrier: otherwise another wave's restage
        // DMA can land in this slot while our ds_reads are still in flight.
        if (k < 4) {
            CFENCE();
            __builtin_amdgcn_s_waitcnt(WAIT_LGKM0);
            __builtin_amdgcn_s_barrier();
            CFENCE();
            const int s = k + 5;
#pragma unroll
            for (int i = 0; i < 2; ++i)
                GLDS16(srcb + ((size_t)ix[s][i] << 7) + (cg << 4),
                       &SL[k % 5][(i << 12) + ldsw]);
#pragma unroll
            for (int i = 0; i < 2; ++i)
                GLDS16(wtb + ((size_t)s << 13) + (i << 12) + ((tid >> 3) << 7) + (cg << 4),
                       &SL[k % 5][8192 + (i << 12) + ldsw]);
            CFENCE();
        }
    }

    // store (D layout: row = quad*4+reg, col = lane&15); wave tile 16 rows
#pragma unroll
    for (int nt = 0; nt < 4; ++nt) {
        int rowb = row0 + (wv << 4) + (quad << 2);
        int col  = (nt << 4) + l15;
#pragma unroll
        for (int r = 0; r < 4; ++r)
            dst[((size_t)(rowb + r) << 6) + col] = (__bf16)acc[nt][r];
    }

    // stats; red[] aliased onto SL[0] (ring fully consumed)
    float* red = (float*)SL[0];
    __syncthreads();
    if (tid < 128) red[tid] = 0.f;
    __syncthreads();
#pragma unroll
    for (int nt = 0; nt < 4; ++nt) {
        float s = 0.f, q = 0.f;
#pragma unroll
        for (int r = 0; r < 4; ++r) { float v = acc[nt][r]; s += v; q += v * v; }
        s += __shfl_xor(s, 16); s += __shfl_xor(s, 32);
        q += __shfl_xor(q, 16); q += __shfl_xor(q, 32);
        if (lane < 16) {
            atomicAdd(&red[(nt << 4) + lane], s);
            atomicAdd(&red[64 + (nt << 4) + lane], q);
        }
    }
    __syncthreads();
    if (tid < 128) atomicAdd(&stat_out[tid], red[tid]);
}

// in-place y = leaky(bn(y)) on bf16
__global__ __launch_bounds__(256) void bnact_kernel(
    __bf16* __restrict__ y, const float* __restrict__ stat,
    const float* __restrict__ gamma, const float* __restrict__ beta)
{
    __shared__ float sc[64], sh[64];
    int tid = threadIdx.x;
    if (tid < 64) {
        float m = stat[tid] * (1.f / NROWS);
        float v = stat[64 + tid] * (1.f / NROWS) - m * m;
        float s = gamma[tid] * rsqrtf(v + EPSBN);
        sc[tid] = s;
        sh[tid] = beta[tid] - m * s;
    }
    __syncthreads();
    size_t base = ((((size_t)blockIdx.x << 8) | tid) << 3);
    int c0 = (int)(base & 63);
    bf16x8_t hv = *(bf16x8_t*)(y + base);
#pragma unroll
    for (int j = 0; j < 8; ++j) {
        float f = (float)hv[j];
        f = leaky_f(f * sc[c0 + j] + sh[c0 + j]);
        hv[j] = (__bf16)f;
    }
    *(bf16x8_t*)(y + base) = hv;
}

// x_new = leaky(bn2(z) + x); z bf16, residual stream fp32 (+bf16 mirror)
__global__ __launch_bounds__(256) void resid_kernel(
    const __bf16* __restrict__ z, const float* __restrict__ xin,
    float* __restrict__ xf, __bf16* __restrict__ xh, float* __restrict__ dout,
    const float* __restrict__ stat, const float* __restrict__ gamma,
    const float* __restrict__ beta, int isfinal)
{
    __shared__ float sc[64], sh[64];
    int tid = threadIdx.x;
    if (tid < 64) {
        float m = stat[tid] * (1.f / NROWS);
        float v = stat[64 + tid] * (1.f / NROWS) - m * m;
        float s = gamma[tid] * rsqrtf(v + EPSBN);
        sc[tid] = s;
        sh[tid] = beta[tid] - m * s;
    }
    __syncthreads();
    size_t base = ((((size_t)blockIdx.x << 8) | tid) << 3);
    int c0 = (int)(base & 63);
    bf16x8_t zv = *(const bf16x8_t*)(z + base);
    float4 xa = *(const float4*)(xin + base);
    float4 xb = *(const float4*)(xin + base + 4);
    float o[8];
#pragma unroll
    for (int j = 0; j < 8; ++j) {
        float xv = (j < 4) ? (&xa.x)[j] : (&xb.x)[j - 4];
        o[j] = leaky_f((float)zv[j] * sc[c0 + j] + sh[c0 + j] + xv);
    }
    if (isfinal) {
        *(float4*)(dout + base)     = make_float4(o[0], o[1], o[2], o[3]);
        *(float4*)(dout + base + 4) = make_float4(o[4], o[5], o[6], o[7]);
    } else {
        *(float4*)(xf + base)     = make_float4(o[0], o[1], o[2], o[3]);
        *(float4*)(xf + base + 4) = make_float4(o[4], o[5], o[6], o[7]);
        bf16x8_t h;
#pragma unroll
        for (int j = 0; j < 8; ++j) h[j] = (__bf16)o[j];
        *(bf16x8_t*)(xh + base) = h;
    }
}

// once-per-call prep: features->bf16, weights->transposed bf16, zero stats,
// premasked transposed indices cidxT[k][n] (masked-out -> NROWS), zero
// sentinel rows. Mask encoding detect: center (k=4) always True -> raw byte
// 13 nonzero iff byte-encoded; zero if int32/float32-encoded.
__global__ __launch_bounds__(256) void prep_kernel(
    const float* __restrict__ feat, const float* __restrict__ w1,
    const float* __restrict__ w2, const int* __restrict__ nidx,
    const unsigned char* __restrict__ mraw,
    __bf16* __restrict__ fh, __bf16* __restrict__ yh,
    __bf16* __restrict__ wtp, int* __restrict__ cidxT,
    float* __restrict__ stats)
{
    size_t t = ((size_t)blockIdx.x << 8) | threadIdx.x;
    if (t < 1024) stats[t] = 0.f;
    if (t < 64) {   // zero sentinel rows
        fh[(size_t)NROWS * 64 + t] = (__bf16)0.f;
        yh[(size_t)NROWS * 64 + t] = (__bf16)0.f;
    }
    if (t < 1048576) {  // features: 8 floats -> 8 bf16 per thread
        size_t i = t << 3;
        float4 a = *(const float4*)(feat + i);
        float4 b = *(const float4*)(feat + i + 4);
        bf16x8_t h;
        h[0] = (__bf16)a.x; h[1] = (__bf16)a.y; h[2] = (__bf16)a.z; h[3] = (__bf16)a.w;
        h[4] = (__bf16)b.x; h[5] = (__bf16)b.y; h[6] = (__bf16)b.z; h[7] = (__bf16)b.w;
        *(bf16x8_t*)(fh + i) = h;
    }
    if (t < 294912) {   // wtp[cv][b][k][d][c] = w[b][k][c][d]
        int o = (int)t;
        int c = o & 63, d = (o >> 6) & 63;
        int kk = o >> 12;              // 0..71
        int k = kk % 9, bb = (kk / 9) & 3, cv = kk / 36;
        const float* w = cv ? w2 : w1;
        float v = w[((size_t)((bb * 9 + k) * 64 + c) << 6) + d];
        wtp[o] = (__bf16)v;
    }
    if (t < 1179648) {  // cidxT[k][n]
        int k = (int)(t >> 17), n = (int)(t & 131071);
        bool bytes_enc = (mraw[13] != 0);
        int e = n * 9 + k;
        bool m = bytes_enc ? (mraw[e] != 0) : (((const unsigned int*)mraw)[e] != 0u);
        cidxT[t] = m ? nidx[e] : NROWS;
    }
}

extern "C" void kernel_launch(void* const* d_in, const int* in_sizes, int n_in,
                              void* d_out, int out_size, void* d_ws, size_t ws_size,
                              hipStream_t stream) {
    const float* feat = (const float*)d_in[0];
    const int* nidx = (const int*)d_in[1];
    const unsigned char* mraw = (const unsigned char*)d_in[2];
    const float* w1 = (const float*)d_in[3];
    const float* g1 = (const float*)d_in[4];
    const float* b1 = (const float*)d_in[5];
    const float* w2 = (const float*)d_in[6];
    const float* g2 = (const float*)d_in[7];
    const float* b2 = (const float*)d_in[8];
    float* out = (float*)d_out;

    char* ws = (char*)d_ws;
    float*  xf    = (float*)ws;                        // 33.55 MB fp32 residual
    __bf16* xh    = (__bf16*)(ws + 33554432);          // (N+1) rows bf16 mirror of x
    __bf16* yh    = (__bf16*)(ws + 50331904);          // (N+1) rows bf16 conv1 out
    __bf16* zh    = (__bf16*)(ws + 67109376);          // N rows bf16 conv2 out
    __bf16* wtp   = (__bf16*)(ws + 83886592);          // 0.59 MB transposed weights
    float*  stats = (float*)(ws + 84476416);           // 8 stages x 128 floats
    int*    cidxT = (int*)(ws + 84480512);             // 4.72 MB premasked idx^T

    prep_kernel<<<4608, 256, 0, stream>>>(feat, w1, w2, nidx, mraw,
                                          xh, yh, wtp, cidxT, stats);

    for (int b = 0; b < 4; ++b) {
        conv_kernel<<<2048, 256, 0, stream>>>(
            xh, cidxT, wtp + (size_t)b * 9 * 4096,
            yh, stats + (size_t)(2 * b) * 128);
        bnact_kernel<<<4096, 256, 0, stream>>>(
            yh, stats + (size_t)(2 * b) * 128, g1 + b * 64, b1 + b * 64);
        conv_kernel<<<2048, 256, 0, stream>>>(
            yh, cidxT, wtp + (size_t)(4 + b) * 9 * 4096,
            zh, stats + (size_t)(2 * b + 1) * 128);
        resid_kernel<<<4096, 256, 0, stream>>>(
            zh, (b == 0) ? feat : xf, xf, xh, out,
            stats + (size_t)(2 * b + 1) * 128, g2 + b * 64, b2 + b * 64,
            (b == 3) ? 1 : 0);
    }
}

// Round 8
// 400.706 us; speedup vs baseline: 1.6551x; 1.6551x over previous
//
#include <hip/hip_runtime.h>
#include <hip/hip_bf16.h>
#include <stdint.h>

#define NROWS 131072
#define EPSBN 1e-5f
#define LEAKK 0.33f

typedef __bf16 bf16x8_t __attribute__((ext_vector_type(8)));
typedef float  f32x4_t  __attribute__((ext_vector_type(4)));

__device__ __forceinline__ float leaky_f(float x) { return fmaxf(x, LEAKK * x); }

#define GLDS16(g, l)                                                          \
    __builtin_amdgcn_global_load_lds(                                         \
        (const __attribute__((address_space(1))) void*)(g),                   \
        (__attribute__((address_space(3))) void*)(l), 16, 0, 0)

// gfx9 waitcnt imm: vmcnt[3:0]|[15:14], expcnt[6:4], lgkmcnt[11:8]
#define WAIT_VM18  0x4F72
#define WAIT_VM10  0x0F7A
#define WAIT_VM8   0x0F78
#define WAIT_VM0   0x0F70
#define WAIT_LGKM0 0xC07F   // lgkmcnt==0, vmcnt/exp off
#define CFENCE() asm volatile("" ::: "memory")

// Gather-GEMM conv via async global_load_lds, 2-deep (r5 structure + race fix).
// out[n,d] = sum_k sum_c src[cidxT[k][n],c] * w[k,c,d]; cidxT premasked
// (masked-out -> row NROWS = zeros). Block: 256 rows, wave tile 64x64.
// A slab (32KB) + B slab (8KB) double-buffered in LDS, staged by
// global_load_lds with per-lane gather addresses; XOR chunk swizzle keeps
// ds_read_b128 at 2-way conflicts (free). Hand vmcnt ledger (verified):
// step d queue = [stage k:10][idx k+2:8][stage k+1:10] -> vm<=18 retires
// stage k exactly. lgkmcnt(0) before the reuse barrier closes the
// ds_read-vs-DMA-overwrite race (proven necessary in r6/r7).
__global__ __launch_bounds__(256, 2) void conv_kernel(
    const __bf16* __restrict__ src,      // (NROWS+1) x 64, row NROWS = zeros
    const int* __restrict__ cidxT,       // [9][NROWS]
    const __bf16* __restrict__ wt,       // [9][64 d][64 c]
    __bf16* __restrict__ dst,
    float* __restrict__ stat_out)
{
    __shared__ char Ab[2][32768];
    __shared__ char Bb[2][8192];

    const int tid  = threadIdx.x;
    const int lane = tid & 63;
    const int wv   = tid >> 6;
    const int quad = lane >> 4;
    const int l15  = lane & 15;
    const int row0 = blockIdx.x << 8;          // 256 rows/block
    const int srow = tid >> 3;                 // staging base row (0..31)
    const int cg   = (tid & 7) ^ (srow & 7);   // swizzled global chunk
    const int ldsl = (tid & 192) << 4;         // wave-uniform lds sub-base
    const int sxor = l15 & 7;

    const char* srcb = (const char*)src;
    const char* wtb  = (const char*)wt;

    f32x4_t acc[4][4];
#pragma unroll
    for (int mt = 0; mt < 4; ++mt)
#pragma unroll
        for (int nt = 0; nt < 4; ++nt)
            acc[mt][nt] = (f32x4_t){0.f, 0.f, 0.f, 0.f};

    int ix[2][8];
    // prologue: idx k=0, idx k=1, stage slab 0
#pragma unroll
    for (int i = 0; i < 8; ++i) ix[0][i] = cidxT[row0 + (i << 5) + srow];
    CFENCE();
#pragma unroll
    for (int i = 0; i < 8; ++i) ix[1][i] = cidxT[NROWS + row0 + (i << 5) + srow];
    CFENCE();
    __builtin_amdgcn_s_waitcnt(WAIT_VM8);      // ix0 ready (ix1 in flight)
#pragma unroll
    for (int i = 0; i < 8; ++i)
        GLDS16(srcb + ((size_t)ix[0][i] << 7) + (cg << 4), &Ab[0][(i << 12) + ldsl]);
#pragma unroll
    for (int i = 0; i < 2; ++i)
        GLDS16(wtb + (((i << 5) + srow) << 7) + (cg << 4), &Bb[0][(i << 12) + ldsl]);
    CFENCE();

#pragma unroll
    for (int k = 0; k < 9; ++k) {
        const int cur = k & 1, nxt = cur ^ 1;
        // a: idx(k+2) into the slot freed by stage-k
        if (k < 7) {
#pragma unroll
            for (int i = 0; i < 8; ++i)
                ix[k & 1][i] = cidxT[(k + 2) * NROWS + row0 + (i << 5) + srow];
        }
        CFENCE();
        // c: issue stage(k+1) (compiler auto-waits for ix[k+1] values)
        if (k < 8) {
            const int* ixu = ix[(k + 1) & 1];
#pragma unroll
            for (int i = 0; i < 8; ++i)
                GLDS16(srcb + ((size_t)ixu[i] << 7) + (cg << 4),
                       &Ab[nxt][(i << 12) + ldsl]);
#pragma unroll
            for (int i = 0; i < 2; ++i)
                GLDS16(wtb + ((size_t)(k + 1) << 13) + (((i << 5) + srow) << 7) + (cg << 4),
                       &Bb[nxt][(i << 12) + ldsl]);
        }
        CFENCE();
        // d: wait stage-k (leaves idx(k+2) + stage(k+1) in flight)
        if (k < 7)       __builtin_amdgcn_s_waitcnt(WAIT_VM18);
        else if (k == 7) __builtin_amdgcn_s_waitcnt(WAIT_VM10);
        else             __builtin_amdgcn_s_waitcnt(WAIT_VM0);
        __builtin_amdgcn_s_barrier();          // e: stage-k visible to all
        // f: fragments + MFMA
        bf16x8_t af[4][2], bq[4][2];
#pragma unroll
        for (int ks = 0; ks < 2; ++ks) {
            const int slot = ((quad | (ks << 2)) ^ sxor) << 4;
#pragma unroll
            for (int mt = 0; mt < 4; ++mt) {
                int m = (wv << 6) + (mt << 4) + l15;
                af[mt][ks] = *(const bf16x8_t*)&Ab[cur][(m << 7) + slot];
            }
#pragma unroll
            for (int nt = 0; nt < 4; ++nt) {
                int d = (nt << 4) + l15;
                bq[nt][ks] = *(const bf16x8_t*)&Bb[cur][(d << 7) + slot];
            }
        }
#pragma unroll
        for (int ks = 0; ks < 2; ++ks)
#pragma unroll
            for (int mt = 0; mt < 4; ++mt)
#pragma unroll
                for (int nt = 0; nt < 4; ++nt)
                    acc[mt][nt] = __builtin_amdgcn_mfma_f32_16x16x32_bf16(
                        af[mt][ks], bq[nt][ks], acc[mt][nt], 0, 0, 0);
        // g: drain own ds_reads, then barrier, before buffer cur is restaged
        CFENCE();
        __builtin_amdgcn_s_waitcnt(WAIT_LGKM0);
        __builtin_amdgcn_s_barrier();
        CFENCE();
    }

    // store (D layout: row = quad*4+reg, col = lane&15)
#pragma unroll
    for (int mt = 0; mt < 4; ++mt) {
        int rowb = row0 + (wv << 6) + (mt << 4) + (quad << 2);
#pragma unroll
        for (int nt = 0; nt < 4; ++nt) {
            int col = (nt << 4) + l15;
#pragma unroll
            for (int r = 0; r < 4; ++r)
                dst[((size_t)(rowb + r) << 6) + col] = (__bf16)acc[mt][nt][r];
        }
    }
    // stats; red[] aliased onto Bb[1] (last consumed at k=7)
    float* red = (float*)Bb[1];
    __syncthreads();
    if (tid < 128) red[tid] = 0.f;
    __syncthreads();
#pragma unroll
    for (int nt = 0; nt < 4; ++nt) {
        float s = 0.f, q = 0.f;
#pragma unroll
        for (int mt = 0; mt < 4; ++mt)
#pragma unroll
            for (int r = 0; r < 4; ++r) { float v = acc[mt][nt][r]; s += v; q += v * v; }
        s += __shfl_xor(s, 16); s += __shfl_xor(s, 32);
        q += __shfl_xor(q, 16); q += __shfl_xor(q, 32);
        if (lane < 16) {
            atomicAdd(&red[(nt << 4) + lane], s);
            atomicAdd(&red[64 + (nt << 4) + lane], q);
        }
    }
    __syncthreads();
    if (tid < 128) atomicAdd(&stat_out[tid], red[tid]);
}

// in-place y = leaky(bn(y)) on bf16
__global__ __launch_bounds__(256) void bnact_kernel(
    __bf16* __restrict__ y, const float* __restrict__ stat,
    const float* __restrict__ gamma, const float* __restrict__ beta)
{
    __shared__ float sc[64], sh[64];
    int tid = threadIdx.x;
    if (tid < 64) {
        float m = stat[tid] * (1.f / NROWS);
        float v = stat[64 + tid] * (1.f / NROWS) - m * m;
        float s = gamma[tid] * rsqrtf(v + EPSBN);
        sc[tid] = s;
        sh[tid] = beta[tid] - m * s;
    }
    __syncthreads();
    size_t base = ((((size_t)blockIdx.x << 8) | tid) << 3);
    int c0 = (int)(base & 63);
    bf16x8_t hv = *(bf16x8_t*)(y + base);
#pragma unroll
    for (int j = 0; j < 8; ++j) {
        float f = (float)hv[j];
        f = leaky_f(f * sc[c0 + j] + sh[c0 + j]);
        hv[j] = (__bf16)f;
    }
    *(bf16x8_t*)(y + base) = hv;
}

// x_new = leaky(bn2(z) + x). Residual stream is bf16-only (xh). Block 0 reads
// feat (fp32); final block writes d_out (fp32) and skips the xh write.
__global__ __launch_bounds__(256) void resid_kernel(
    const __bf16* __restrict__ z, const float* __restrict__ featin,
    __bf16* __restrict__ xh, float* __restrict__ dout,
    const float* __restrict__ stat, const float* __restrict__ gamma,
    const float* __restrict__ beta, int isfirst, int isfinal)
{
    __shared__ float sc[64], sh[64];
    int tid = threadIdx.x;
    if (tid < 64) {
        float m = stat[tid] * (1.f / NROWS);
        float v = stat[64 + tid] * (1.f / NROWS) - m * m;
        float s = gamma[tid] * rsqrtf(v + EPSBN);
        sc[tid] = s;
        sh[tid] = beta[tid] - m * s;
    }
    __syncthreads();
    size_t base = ((((size_t)blockIdx.x << 8) | tid) << 3);
    int c0 = (int)(base & 63);
    bf16x8_t zv = *(const bf16x8_t*)(z + base);
    float xv[8];
    if (isfirst) {
        float4 xa = *(const float4*)(featin + base);
        float4 xb = *(const float4*)(featin + base + 4);
#pragma unroll
        for (int j = 0; j < 4; ++j) { xv[j] = (&xa.x)[j]; xv[4 + j] = (&xb.x)[j]; }
    } else {
        bf16x8_t xr = *(const bf16x8_t*)(xh + base);
#pragma unroll
        for (int j = 0; j < 8; ++j) xv[j] = (float)xr[j];
    }
    float o[8];
#pragma unroll
    for (int j = 0; j < 8; ++j)
        o[j] = leaky_f((float)zv[j] * sc[c0 + j] + sh[c0 + j] + xv[j]);
    if (isfinal) {
        *(float4*)(dout + base)     = make_float4(o[0], o[1], o[2], o[3]);
        *(float4*)(dout + base + 4) = make_float4(o[4], o[5], o[6], o[7]);
    } else {
        bf16x8_t h;
#pragma unroll
        for (int j = 0; j < 8; ++j) h[j] = (__bf16)o[j];
        *(bf16x8_t*)(xh + base) = h;
    }
}

// once-per-call prep: features->bf16 mirror, weights->transposed bf16, zero
// stats, premasked transposed indices cidxT[k][n] (masked-out -> NROWS;
// built thread-per-row: coalesced 9-entry reads + 9 coalesced stores),
// zero sentinel rows. Mask encoding detect: center (k=4) always True ->
// raw byte 13 nonzero iff byte-encoded; zero if int32/float32-encoded.
__global__ __launch_bounds__(256) void prep_kernel(
    const float* __restrict__ feat, const float* __restrict__ w1,
    const float* __restrict__ w2, const int* __restrict__ nidx,
    const unsigned char* __restrict__ mraw,
    __bf16* __restrict__ fh, __bf16* __restrict__ yh,
    __bf16* __restrict__ wtp, int* __restrict__ cidxT,
    float* __restrict__ stats)
{
    size_t t = ((size_t)blockIdx.x << 8) | threadIdx.x;
    if (t < 1024) stats[t] = 0.f;
    if (t < 64) {   // zero sentinel rows
        fh[(size_t)NROWS * 64 + t] = (__bf16)0.f;
        yh[(size_t)NROWS * 64 + t] = (__bf16)0.f;
    }
    if (t < 1048576) {  // features: 8 floats -> 8 bf16 per thread
        size_t i = t << 3;
        float4 a = *(const float4*)(feat + i);
        float4 b = *(const float4*)(feat + i + 4);
        bf16x8_t h;
        h[0] = (__bf16)a.x; h[1] = (__bf16)a.y; h[2] = (__bf16)a.z; h[3] = (__bf16)a.w;
        h[4] = (__bf16)b.x; h[5] = (__bf16)b.y; h[6] = (__bf16)b.z; h[7] = (__bf16)b.w;
        *(bf16x8_t*)(fh + i) = h;
    }
    if (t < 294912) {   // wtp[cv][b][k][d][c] = w[b][k][c][d]
        int o = (int)t;
        int c = o & 63, d = (o >> 6) & 63;
        int kk = o >> 12;              // 0..71
        int k = kk % 9, bb = (kk / 9) & 3, cv = kk / 36;
        const float* w = cv ? w2 : w1;
        float v = w[((size_t)((bb * 9 + k) * 64 + c) << 6) + d];
        wtp[o] = (__bf16)v;
    }
    if (t < NROWS) {    // cidxT: one thread per row n, 9 entries
        int n = (int)t;
        bool benc = (mraw[13] != 0);
        const unsigned int* mw = (const unsigned int*)mraw;
#pragma unroll
        for (int j = 0; j < 9; ++j) {
            int e = n * 9 + j;
            bool m = benc ? (mraw[e] != 0) : (mw[e] != 0u);
            cidxT[j * NROWS + n] = m ? nidx[e] : NROWS;
        }
    }
}

extern "C" void kernel_launch(void* const* d_in, const int* in_sizes, int n_in,
                              void* d_out, int out_size, void* d_ws, size_t ws_size,
                              hipStream_t stream) {
    const float* feat = (const float*)d_in[0];
    const int* nidx = (const int*)d_in[1];
    const unsigned char* mraw = (const unsigned char*)d_in[2];
    const float* w1 = (const float*)d_in[3];
    const float* g1 = (const float*)d_in[4];
    const float* b1 = (const float*)d_in[5];
    const float* w2 = (const float*)d_in[6];
    const float* g2 = (const float*)d_in[7];
    const float* b2 = (const float*)d_in[8];
    float* out = (float*)d_out;

    char* ws = (char*)d_ws;
    __bf16* xh    = (__bf16*)ws;                       // (N+1)x64 bf16 residual
    __bf16* yh    = (__bf16*)(ws + 17825792);          // (N+1)x64 bf16 conv1 out
    __bf16* zh    = (__bf16*)(ws + 35651584);          // N x64 bf16 conv2 out
    __bf16* wtp   = (__bf16*)(ws + 53477376);          // 0.59 MB transposed weights
    float*  stats = (float*)(ws + 54525952);           // 8 stages x 128 floats
    int*    cidxT = (int*)(ws + 54591488);             // 4.72 MB premasked idx^T

    prep_kernel<<<4096, 256, 0, stream>>>(feat, w1, w2, nidx, mraw,
                                          xh, yh, wtp, cidxT, stats);

    for (int b = 0; b < 4; ++b) {
        conv_kernel<<<512, 256, 0, stream>>>(
            xh, cidxT, wtp + (size_t)b * 9 * 4096,
            yh, stats + (size_t)(2 * b) * 128);
        bnact_kernel<<<4096, 256, 0, stream>>>(
            yh, stats + (size_t)(2 * b) * 128, g1 + b * 64, b1 + b * 64);
        conv_kernel<<<512, 256, 0, stream>>>(
            yh, cidxT, wtp + (size_t)(4 + b) * 9 * 4096,
            zh, stats + (size_t)(2 * b + 1) * 128);
        resid_kernel<<<4096, 256, 0, stream>>>(
            zh, feat, xh, out,
            stats + (size_t)(2 * b + 1) * 128, g2 + b * 64, b2 + b * 64,
            (b == 0) ? 1 : 0, (b == 3) ? 1 : 0);
    }
}